// Round 17
// baseline (668.839 us; speedup 1.0000x reference)
//
#include <hip/hip_runtime.h>
#include <hip/hip_bf16.h>
#include <stdint.h>

#define TSTEPS 4

typedef __bf16 bf16_t;
typedef __attribute__((ext_vector_type(8))) __bf16 bf16x8;
typedef __attribute__((ext_vector_type(16))) float f32x16;
typedef __attribute__((ext_vector_type(4))) unsigned short ushort4v;

union frag_u { bf16x8 v; uint32_t d[4]; unsigned short u[8]; };

// gfx9 s_waitcnt imm: vm [3:0]|[15:14]; exp [6:4]; lgkm [11:8].
#define WT_VM4_LG0  0x074   // vmcnt(4) lgkmcnt(0)
#define WT_VM4      0xF74   // vmcnt(4)
#define WT_LG0      0xC07F  // lgkmcnt(0), vm unbounded
#define WT_VM0_LG0  0x070   // full drain (tail)

// ---------------------------------------------------------------------------
// R33 = R28 (full-LDS staging, conflict-free A, 104us / 56% MfmaUtil) with
// 2-kb SUPER-STEPS: 16 MFMAs (516 matrix-cyc) per {vmcnt + barrier + frag
// read bundle}. R28's step wall ~1465cy pays a ~690cy fixed tax per 258
// matrix-cyc; halving the sync rate amortizes it. (R26 tested 2-kb phases
// and was null -- but in the pre-R27 VMEM-queue-bound regime; R28's regime
// is sync/fixed-cost-bound, where this mechanism acts. Regime-gated retry.)
// Ring-3 of 16KB PAIR-slabs (kb-even at +0, kb-odd at +8KB). Per step:
// stage pair i+2 (4 DMA, same 2/kb rate), vmcnt(4)+lgkm(0) -> drains pair
// i+1's stage (full 2-kb step of latency cover), 16 MFMAs, one barrier,
// 12 hoisted ds_reads for pair i+1.
// Hazard: STAGE_PAIR(i+2) overwrites pair i-1's slab; its ds_reads were
// drained at step i-1's lgkm(0) < step i-1's barrier < this stage's issue
// (all waves). Safe. lb(256,3): frag regs +32 vs R28; avoid (256,4)'s
// 128-reg cliff (R29 lesson). LDS 51KB -> 3 blocks/CU = measured residency.
// Spike bytes 0x3F -> v_perm high-byte = bf16 0.5; B pre-doubled (exact
// exponent bump) so products are bitwise 1.0*w (R19/R21/R22-proven).
// A layout: [m_blk32][kb16][t][half][row0..31][8 bytes], byte = 0x00/0x3F.
// B-frag layout: packet ((n>>5)*NKB + (k>>4))*512 + ((n&31)+32*((k>>3)&1))*8
// + (k&7), bf16, value = 2*w_hi / 2*w_lo.
// Fused mean-over-L in LAST epilogue kept (R24 win).
// ---------------------------------------------------------------------------

// ---------------------------------------------------------------------------
// Stage 1: input LIF encoder -> spike 0x3F bytes. C=128. XLA-exact LIF.
// ---------------------------------------------------------------------------
__global__ void spike_encode_i8(const float* __restrict__ x,
                                uint8_t* __restrict__ s1)
{
    const int C = 128;
    int tid = blockIdx.x * blockDim.x + threadIdx.x;  // 65536 = 256*8*32
    int row = tid & 31;
    int kb  = (tid >> 5) & 7;
    int m_blk = tid >> 8;
    int m = m_blk * 32 + row;
    const float* px = x + (size_t)m * C + kb * 16;
    float xv[16];
#pragma unroll
    for (int j = 0; j < 16; j += 4) {
        float4 t4 = *(const float4*)(px + j);
        xv[j] = t4.x; xv[j+1] = t4.y; xv[j+2] = t4.z; xv[j+3] = t4.w;
    }
    float v[16];
#pragma unroll
    for (int j = 0; j < 16; ++j) v[j] = 0.0f;
    uint8_t* pkt0 = s1 + (size_t)(m_blk * 8 + kb) * 4 * 512;
#pragma unroll
    for (int t = 0; t < TSTEPS; ++t) {
        uint32_t dw[4] = {0u, 0u, 0u, 0u};
#pragma unroll
        for (int j = 0; j < 16; ++j) {
            float vv = __fadd_rn(v[j], __fmul_rn(__fsub_rn(xv[j], v[j]), 0.5f));
            bool sp = (vv >= 1.0f);
            dw[j >> 2] |= sp ? (0x3Fu << ((j & 3) * 8)) : 0u;
            v[j] = sp ? 0.0f : vv;
        }
        // [t][half][row][8B]: k0-7 at row*8, k8-15 at 256+row*8
        uint2 lo2; lo2.x = dw[0]; lo2.y = dw[1];
        uint2 hi2; hi2.x = dw[2]; hi2.y = dw[3];
        *(uint2*)(pkt0 + (size_t)t * 512 + row * 8)       = lo2;
        *(uint2*)(pkt0 + (size_t)t * 512 + 256 + row * 8) = hi2;
    }
}

// ---------------------------------------------------------------------------
// Weight prep: W [K][N] fp32 -> 2*hi / 2*lo bf16 split in B-frag layout.
// ---------------------------------------------------------------------------
__global__ void split_transpose_all(const float* __restrict__ enc_W,
                                    const float* __restrict__ W_cells,
                                    bf16_t* __restrict__ W1h, bf16_t* __restrict__ W1l,
                                    bf16_t* __restrict__ W2h, bf16_t* __restrict__ W2l,
                                    bf16_t* __restrict__ W3h, bf16_t* __restrict__ W3l)
{
    const int N = 1024;
    const float* W;
    bf16_t *hi, *lo;
    int K;
    if (blockIdx.z == 0) {
        if (blockIdx.x >= 4) return;
        W = enc_W; hi = W1h; lo = W1l; K = 128;
    } else if (blockIdx.z == 1) {
        W = W_cells; hi = W2h; lo = W2l; K = 1024;
    } else {
        W = W_cells + (size_t)1024 * 1024; hi = W3h; lo = W3l; K = 1024;
    }
    const int NKB = K >> 4;
    __shared__ float tile[32][33];
    int k0 = blockIdx.x * 32, n0 = blockIdx.y * 32;
    int tx = threadIdx.x & 31, ty = threadIdx.x >> 5;
    for (int kk = ty; kk < 32; kk += 8)
        tile[kk][tx] = W[(size_t)(k0 + kk) * N + n0 + tx];
    __syncthreads();

    const int nn = tx;
    const int oc = ty;            // 0..7
    const int o2 = oc & 3;        // k-octet
    const bool isLo = (oc >> 2) != 0;
    const int kblk = (k0 >> 4) + (o2 >> 1);
    const int lane_in_packet = nn + 32 * (o2 & 1);

    frag_u f;
#pragma unroll
    for (int j = 0; j < 8; ++j) {
        float wv = tile[o2 * 8 + j][nn];
        bf16_t h = (bf16_t)wv;                          // original hi rounding
        bf16_t l = (bf16_t)(wv - (float)h);             // original lo rounding
        f.v[j] = isLo ? (bf16_t)(2.0f * (float)l)       // exact doubling
                      : (bf16_t)(2.0f * (float)h);
    }
    bf16_t* dst = (isLo ? lo : hi)
        + ((size_t)((n0 + nn) >> 5) * NKB + kblk) * 512 + lane_in_packet * 8;
    *(bf16x8*)dst = f.v;
}

// ---------------------------------------------------------------------------
// Fused MFMA GEMM + multistep LIF. R33: 2-kb super-steps, ring-3 pair-slabs,
// conflict-free A reads, counted waits, fused mean (LAST).
// ---------------------------------------------------------------------------
template <int K, bool LAST>
__global__ __launch_bounds__(256, 3)
void gemm_lif_mfma(const uint8_t* __restrict__ Abytes,
                   const bf16_t* __restrict__ Bh,
                   const bf16_t* __restrict__ Bl,
                   const float* __restrict__ bias,
                   uint8_t* __restrict__ Sbytes,
                   float* __restrict__ Out,
                   int M, int N)
{
    constexpr int NKB = K >> 4;                 // 8 or 64
    constexpr int NP  = NKB >> 1;               // pairs (>= 4, even)
    // Pair-slab 16KB: [kb-even 8KB | kb-odd 8KB]; each 8KB half:
    // [A m0 2KB | A m1 2KB | B n0 hi 1KB | B n0 lo | B n1 hi | B n1 lo]
    __shared__ __align__(16) uint8_t ldsR[3][16384];     // 48KB ring
    __shared__ __align__(8) unsigned short sh[4][256];   // epilogue, per-wave

    const int tid = threadIdx.x;
    const int lane = tid & 63;
    const int wid = tid >> 6;
    const int l31 = lane & 31;
    const int half = lane >> 5;

    // XCD-locality swizzle (R18): XCD x owns m_t in [x*16, x*16+16);
    // walk nh(2) x mloc(16) x n8(8). Bijective.
    const int bid = blockIdx.x;
    const int xcd = bid & 7;
    const int j   = bid >> 3;                   // 0..255
    const int nh   = j >> 7;                    // 0..1
    const int r    = j & 127;
    const int mloc = r >> 3;                    // 0..15
    const int n_t  = nh * 8 + (r & 7);          // 0..15
    const int m_t  = xcd * 16 + mloc;           // 0..127

    const int m0 = m_t * 64, n0 = n_t * 64;
    const int wave_m = (wid & 1) * 32;
    const int wave_n = (wid >> 1) * 32;
    const int m_blk = (m0 + wave_m) >> 5;

    // ---- staging assignment: per kb, wave wid stages 2 of 8 1KB chunks ----
    const uint8_t* src0;
    const uint8_t* src1;
    int sstride, d0off, d1off;
    if (wid < 2) {
        // A chunks: m_local = wid; 2KB/kb contiguous ([t][half][row][8B])
        const uint8_t* base = Abytes + ((size_t)(m0 >> 5) + wid) * NKB * 2048;
        src0 = base + (lane << 4);
        src1 = base + 1024 + (lane << 4);
        sstride = 2048;
        d0off = wid * 2048;
        d1off = d0off + 1024;
    } else {
        // B chunks: n_local = wid-2; hi and lo planes, 1KB/kb each
        const int nl = wid - 2;
        src0 = (const uint8_t*)(Bh + ((size_t)(n0 >> 5) + nl) * NKB * 512)
               + (lane << 4);
        src1 = (const uint8_t*)(Bl + ((size_t)(n0 >> 5) + nl) * NKB * 512)
               + (lane << 4);
        sstride = 1024;
        d0off = 4096 + nl * 2048;
        d1off = d0off + 1024;
    }
    uint8_t* ringBase = &ldsR[0][0];

    // ---- consumer fragment addresses (within 8KB kb-half) ----
    // A: (wid&1)*2048 + t*512 + half*256 + l31*8  (uint2, conflict-free)
    // B: 4096 + (wid>>1)*2048 (+1024 lo) + lane*16 (bf16x8)
    const int aRdOff = (wid & 1) * 2048 + half * 256 + l31 * 8;
    const int bRdOff = 4096 + ((wid >> 1) << 11) + (lane << 4);

    f32x16 acc[TSTEPS];
#pragma unroll
    for (int t = 0; t < TSTEPS; ++t)
        for (int rr = 0; rr < 16; ++rr) acc[t][rr] = 0.0f;

    uint2 fmA[4], fmB[4];
    bf16x8 chA, clA, chB, clB;

// stage one kb into pair-slab offset po_ (+hb_ = 0 or 8192 for kb parity)
#define STAGE1(kb_, po_, hb_) {                                               \
    __builtin_amdgcn_global_load_lds(                                         \
        (const __attribute__((address_space(1))) uint32_t*)                   \
            (src0 + (size_t)(kb_) * sstride),                                 \
        (__attribute__((address_space(3))) uint32_t*)                         \
            (ringBase + (po_) + (hb_) + d0off), 16, 0, 0);                    \
    __builtin_amdgcn_global_load_lds(                                         \
        (const __attribute__((address_space(1))) uint32_t*)                   \
            (src1 + (size_t)(kb_) * sstride),                                 \
        (__attribute__((address_space(3))) uint32_t*)                         \
            (ringBase + (po_) + (hb_) + d1off), 16, 0, 0);                    \
    }

#define STAGE_PAIR(p_, po_) {                                                \
        STAGE1(2 * (p_),     po_, 0);                                        \
        STAGE1(2 * (p_) + 1, po_, 8192);                                     \
    }

#define FRAGRD_PAIR(po_) {                                                   \
        const uint8_t* sa = ringBase + (po_);                                \
        fmA[0] = *(const uint2*)(sa + aRdOff);                               \
        fmA[1] = *(const uint2*)(sa + aRdOff + 512);                         \
        fmA[2] = *(const uint2*)(sa + aRdOff + 1024);                        \
        fmA[3] = *(const uint2*)(sa + aRdOff + 1536);                        \
        chA = *(const bf16x8*)(sa + bRdOff);                                 \
        clA = *(const bf16x8*)(sa + bRdOff + 1024);                          \
        const uint8_t* sb = sa + 8192;                                       \
        fmB[0] = *(const uint2*)(sb + aRdOff);                               \
        fmB[1] = *(const uint2*)(sb + aRdOff + 512);                         \
        fmB[2] = *(const uint2*)(sb + aRdOff + 1024);                        \
        fmB[3] = *(const uint2*)(sb + aRdOff + 1536);                        \
        chB = *(const bf16x8*)(sb + bRdOff);                                 \
        clB = *(const bf16x8*)(sb + bRdOff + 1024);                          \
    }

// byte 0x3F -> high byte of each 16-bit half = 0x3F00 = bf16 0.5 (1 perm/dw)
#define EXPANDF(a_, f_) {                                                    \
        (f_).d[0] = __builtin_amdgcn_perm((a_).x, 0u, 0x05000400u);          \
        (f_).d[1] = __builtin_amdgcn_perm((a_).x, 0u, 0x07000600u);          \
        (f_).d[2] = __builtin_amdgcn_perm((a_).y, 0u, 0x05000400u);          \
        (f_).d[3] = __builtin_amdgcn_perm((a_).y, 0u, 0x07000600u);          \
    }

#define MFMAS1(fm_, fh_, fl_) {                                              \
        frag_u af0, af1, af2, af3;                                           \
        EXPANDF((fm_)[0], af0);                                              \
        EXPANDF((fm_)[1], af1);                                              \
        EXPANDF((fm_)[2], af2);                                              \
        EXPANDF((fm_)[3], af3);                                              \
        acc[0] = __builtin_amdgcn_mfma_f32_32x32x16_bf16(af0.v, fh_, acc[0], 0, 0, 0); \
        acc[1] = __builtin_amdgcn_mfma_f32_32x32x16_bf16(af1.v, fh_, acc[1], 0, 0, 0); \
        acc[2] = __builtin_amdgcn_mfma_f32_32x32x16_bf16(af2.v, fh_, acc[2], 0, 0, 0); \
        acc[3] = __builtin_amdgcn_mfma_f32_32x32x16_bf16(af3.v, fh_, acc[3], 0, 0, 0); \
        acc[0] = __builtin_amdgcn_mfma_f32_32x32x16_bf16(af0.v, fl_, acc[0], 0, 0, 0); \
        acc[1] = __builtin_amdgcn_mfma_f32_32x32x16_bf16(af1.v, fl_, acc[1], 0, 0, 0); \
        acc[2] = __builtin_amdgcn_mfma_f32_32x32x16_bf16(af2.v, fl_, acc[2], 0, 0, 0); \
        acc[3] = __builtin_amdgcn_mfma_f32_32x32x16_bf16(af3.v, fl_, acc[3], 0, 0, 0); \
    }

    // Prologue: stage pairs 0,1 (8 VMEM); drain pair0 (4 newest remain);
    // barrier; read pair0 frags.
    STAGE_PAIR(0, 0);
    STAGE_PAIR(1, 16384);
    __builtin_amdgcn_s_waitcnt(WT_VM4);
    asm volatile("" ::: "memory");
    __builtin_amdgcn_s_barrier();
    asm volatile("" ::: "memory");
    FRAGRD_PAIR(0);

    // Steady state: step i computes pair i (frags pre-read), stages pair
    // i+2 into the rotating slab, publishes pair i+1.
    // vmcnt(4)+lgkm(0): outstanding = stage(pair i+2)'s 4 -> drains
    // stage(pair i+1) (issued one FULL 2-kb step ago) + this pair's frag
    // reads. One barrier per 2 kb. Hazard: slab os held pair i-1, whose
    // ds_reads were drained at step i-1's lgkm(0) < step i-1's barrier <
    // this stage (all waves ordered by that barrier). Safe.
    {
        int oc = 0, orr = 16384, os = 32768;
        for (int p = 0; p < NP - 2; ++p) {
            STAGE_PAIR(p + 2, os);
            __builtin_amdgcn_s_waitcnt(WT_VM4_LG0);
            asm volatile("" ::: "memory");
            MFMAS1(fmA, chA, clA);
            MFMAS1(fmB, chB, clB);
            __builtin_amdgcn_s_barrier();
            asm volatile("" ::: "memory");
            FRAGRD_PAIR(orr);
            int tmp = oc; oc = orr; orr = os; os = tmp;
        }
        // Step NP-2: nothing to stage; drain stage(pair NP-1) + frag reads.
        __builtin_amdgcn_s_waitcnt(WT_VM0_LG0);
        asm volatile("" ::: "memory");
        MFMAS1(fmA, chA, clA);
        MFMAS1(fmB, chB, clB);
        __builtin_amdgcn_s_barrier();
        asm volatile("" ::: "memory");
        FRAGRD_PAIR(orr);
        // Step NP-1: final.
        __builtin_amdgcn_s_waitcnt(WT_LG0);
        asm volatile("" ::: "memory");
        MFMAS1(fmA, chA, clA);
        MFMAS1(fmB, chB, clB);
    }

#undef MFMAS1
#undef EXPANDF
#undef FRAGRD_PAIR
#undef STAGE_PAIR
#undef STAGE1

    // --- LIF epilogue: t-scan in registers (XLA-exact arithmetic) ---
    const float bv = bias[n0 + wave_n + l31];
    f32x16 vmem;
#pragma unroll
    for (int rr = 0; rr < 16; ++rr) vmem[rr] = 0.0f;
    uint64_t bits = 0ull;
    unsigned short* myt = &sh[wid][0];          // [row][kb][t] = [32][2][4]

    const int NKBo = N >> 4;
    const int kbase = (n0 + wave_n) >> 4;

    for (int t = 0; t < TSTEPS; ++t) {
#pragma unroll
        for (int rr = 0; rr < 16; ++rr) {
            float y = __fadd_rn(acc[t][rr], bv);
            float vv = vmem[rr];
            vv = __fadd_rn(vv, __fmul_rn(__fsub_rn(y, vv), 0.5f));
            bool sp = (vv >= 1.0f);
            vmem[rr] = sp ? 0.0f : vv;
            if (LAST) {
                bits |= sp ? (1ull << (rr * 4 + t)) : 0ull;
            } else {
                unsigned long long b = __ballot(sp);
                if (l31 == 0) {
                    uint32_t hb = (uint32_t)(b >> (half * 32));
                    int rowi = (rr & 3) + 8 * (rr >> 2) + 4 * half;
                    myt[(rowi * 2 + 0) * 4 + t] = (unsigned short)hb;
                    myt[(rowi * 2 + 1) * 4 + t] = (unsigned short)(hb >> 16);
                }
            }
        }
    }

    if (LAST) {
        // Out writes + fused mean-over-L. All values multiples of 2^-11,
        // totals <= 1 -> fp32 atomics exact and order-independent.
        float psum = 0.0f;
#pragma unroll
        for (int rr = 0; rr < 16; ++rr) {
            int m_r = (rr & 3) + 8 * (rr >> 2) + 4 * half;
            int m = m0 + wave_m + m_r;
            int n = n0 + wave_n + l31;
            int cnt = __popc((unsigned)((bits >> (rr * 4)) & 0xFull));
            float val = 0.25f * (float)cnt;
            Out[(size_t)m * N + n] = val;
            psum += val;                       // exact: multiples of 0.25
        }
        // combine the two halves (same n, other 16 m's of the 32-row blk)
        psum += __shfl_xor(psum, 32, 64);
        if (half == 0) {
            float* out2 = Out + (size_t)M * N;
            int b = m0 >> 9;                   // m0 multiple of 64; L = 512
            int n = n0 + wave_n + l31;
            atomicAdd(out2 + (size_t)b * N + n, psum * (1.0f / 512.0f));
        }
    } else {
        // Emit next-stage A in [t][half][row][8B] packet layout.
        const ushort4v pk = *(const ushort4v*)&myt[(l31 * 2 + half) * 4];
        uint8_t* pkt0 = Sbytes
            + ((size_t)m_blk * NKBo + kbase + half) * 4 * 512;
#pragma unroll
        for (int t = 0; t < TSTEPS; ++t) {
            uint32_t m16 = pk[t];
            uint32_t b0 = (((m16      ) & 0xFu) * 0x00204081u & 0x01010101u) * 0x3Fu;
            uint32_t b1 = (((m16 >>  4) & 0xFu) * 0x00204081u & 0x01010101u) * 0x3Fu;
            uint32_t b2 = (((m16 >>  8) & 0xFu) * 0x00204081u & 0x01010101u) * 0x3Fu;
            uint32_t b3 = (((m16 >> 12) & 0xFu) * 0x00204081u & 0x01010101u) * 0x3Fu;
            uint2 lo2; lo2.x = b0; lo2.y = b1;
            uint2 hi2; hi2.x = b2; hi2.y = b3;
            *(uint2*)(pkt0 + (size_t)t * 512 + l31 * 8)       = lo2;
            *(uint2*)(pkt0 + (size_t)t * 512 + 256 + l31 * 8) = hi2;
        }
    }
}

// ---------------------------------------------------------------------------
// Zero out2 (graph-capture-safe replacement for hipMemsetAsync).
// ---------------------------------------------------------------------------
__global__ void zero_out2(float* __restrict__ out2, int n)
{
    int i = blockIdx.x * blockDim.x + threadIdx.x;
    if (i < n) out2[i] = 0.0f;
}

// ---------------------------------------------------------------------------
extern "C" void kernel_launch(void* const* d_in, const int* in_sizes, int n_in,
                              void* d_out, int out_size, void* d_ws, size_t ws_size,
                              hipStream_t stream)
{
    const float* inputs  = (const float*)d_in[0];  // [16,512,128]
    const float* enc_W   = (const float*)d_in[1];  // [128,1024]
    const float* enc_b   = (const float*)d_in[2];  // [1024]
    const float* W_cells = (const float*)d_in[3];  // [2,1024,1024]
    const float* b_cells = (const float*)d_in[4];  // [2,1024]

    const int B = 16, L = 512, C = 128, D = 1024;
    const int M = B * L;  // 8192

    // ws: s1 i8 4MB | W1h/l 0.5MB | W2h/l 4MB | W3h/l 4MB | h0 32MB | h1 32MB
    char* ws = (char*)d_ws;
    size_t off = 0;
    uint8_t* s1 = (uint8_t*)(ws + off);
    off += (size_t)(M / 32) * (C / 16) * 4 * 32 * 16;
    bf16_t* W1h = (bf16_t*)(ws + off); off += (size_t)C * D * 2;
    bf16_t* W1l = (bf16_t*)(ws + off); off += (size_t)C * D * 2;
    bf16_t* W2h = (bf16_t*)(ws + off); off += (size_t)D * D * 2;
    bf16_t* W2l = (bf16_t*)(ws + off); off += (size_t)D * D * 2;
    bf16_t* W3h = (bf16_t*)(ws + off); off += (size_t)D * D * 2;
    bf16_t* W3l = (bf16_t*)(ws + off); off += (size_t)D * D * 2;
    uint8_t* h0 = (uint8_t*)(ws + off);
    off += (size_t)(M / 32) * (D / 16) * 4 * 32 * 16;
    uint8_t* h1 = (uint8_t*)(ws + off);

    float* out  = (float*)d_out;          // [M, D]
    float* out2 = out + (size_t)M * D;    // [B, D]

    split_transpose_all<<<dim3(32, 32, 3), 256, 0, stream>>>(
        enc_W, W_cells, W1h, W1l, W2h, W2l, W3h, W3l);

    spike_encode_i8<<<256, 256, 0, stream>>>(inputs, s1);

    zero_out2<<<(B * D + 255) / 256, 256, 0, stream>>>(out2, B * D);

    const int nblocks = (M / 64) * (D / 64);   // 2048
    gemm_lif_mfma<128, false><<<nblocks, 256, 0, stream>>>(
        s1, W1h, W1l, enc_b, h0, nullptr, M, D);
    gemm_lif_mfma<1024, false><<<nblocks, 256, 0, stream>>>(
        h0, W2h, W2l, b_cells, h1, nullptr, M, D);
    gemm_lif_mfma<1024, true><<<nblocks, 256, 0, stream>>>(
        h1, W3h, W3l, b_cells + D, nullptr, out, M, D);
}

// Round 18
// 278.764 us; speedup vs baseline: 2.3993x; 2.3993x over previous
//
#include <hip/hip_runtime.h>
#include <hip/hip_bf16.h>
#include <stdint.h>

#define TSTEPS 4

typedef __bf16 bf16_t;
typedef __attribute__((ext_vector_type(8))) __bf16 bf16x8;
typedef __attribute__((ext_vector_type(16))) float f32x16;
typedef __attribute__((ext_vector_type(4))) unsigned short ushort4v;

union frag_u { bf16x8 v; uint32_t d[4]; unsigned short u[8]; };

// gfx9 s_waitcnt imm: vm [3:0]|[15:14]; exp [6:4]; lgkm [11:8].
#define WT_VM2_LG0  0x072   // vmcnt(2) lgkmcnt(0)
#define WT_VM2      0xF72   // vmcnt(2)
#define WT_LG0      0xC07F  // lgkmcnt(0), vm unbounded
#define WT_VM0_LG0  0x070   // full drain (tail)

// ---------------------------------------------------------------------------
// R34 = exact revert to R28 (best verified: 278.2us total, big GEMM 104us,
// MfmaUtil 56%). R31 (pre-expanded bf16 A: +slab, -occupancy), R32
// (barrier-free self-staging: 2x VMEM ops, VGPR 96), and R33 (2-kb
// super-steps: fragment-register cliff -> scratch spills, 628MB writes)
// each attacked the residual ~44% non-MFMA time and all regressed.
// R28 stands as the local optimum of this kernel family:
//   per-wave step = 258 matrix-cyc + ~640cy {2 DMA + 6 DS + 16 perm +
//   vmcnt/lgkm + barrier} with 3 blocks/CU; every lever (prefetch depth,
//   VALU count, swizzle, byte volume, bank conflicts, occupancy, setprio,
//   phase width) tested null-or-negative around this point.
// Structure: full-LDS staging via global_load_lds (2 VMEM + 6 DS per
// wave-step — the R27 breakthrough), ring-4 slabs, conflict-free A packet
// [t][half][row][8B], counted waits (vmcnt never 0 mid-loop), XCD swizzle,
// LIF epilogue in registers, fused mean-over-L (LAST).
// Spike bytes 0x3F -> v_perm high-byte = bf16 0.5; B pre-doubled (exact
// exponent bump) so products are bitwise 1.0*w. absmax 0 maintained.
// ---------------------------------------------------------------------------

// ---------------------------------------------------------------------------
// Stage 1: input LIF encoder -> spike 0x3F bytes. C=128. XLA-exact LIF.
// ---------------------------------------------------------------------------
__global__ void spike_encode_i8(const float* __restrict__ x,
                                uint8_t* __restrict__ s1)
{
    const int C = 128;
    int tid = blockIdx.x * blockDim.x + threadIdx.x;  // 65536 = 256*8*32
    int row = tid & 31;
    int kb  = (tid >> 5) & 7;
    int m_blk = tid >> 8;
    int m = m_blk * 32 + row;
    const float* px = x + (size_t)m * C + kb * 16;
    float xv[16];
#pragma unroll
    for (int j = 0; j < 16; j += 4) {
        float4 t4 = *(const float4*)(px + j);
        xv[j] = t4.x; xv[j+1] = t4.y; xv[j+2] = t4.z; xv[j+3] = t4.w;
    }
    float v[16];
#pragma unroll
    for (int j = 0; j < 16; ++j) v[j] = 0.0f;
    uint8_t* pkt0 = s1 + (size_t)(m_blk * 8 + kb) * 4 * 512;
#pragma unroll
    for (int t = 0; t < TSTEPS; ++t) {
        uint32_t dw[4] = {0u, 0u, 0u, 0u};
#pragma unroll
        for (int j = 0; j < 16; ++j) {
            float vv = __fadd_rn(v[j], __fmul_rn(__fsub_rn(xv[j], v[j]), 0.5f));
            bool sp = (vv >= 1.0f);
            dw[j >> 2] |= sp ? (0x3Fu << ((j & 3) * 8)) : 0u;
            v[j] = sp ? 0.0f : vv;
        }
        // [t][half][row][8B]: k0-7 at row*8, k8-15 at 256+row*8
        uint2 lo2; lo2.x = dw[0]; lo2.y = dw[1];
        uint2 hi2; hi2.x = dw[2]; hi2.y = dw[3];
        *(uint2*)(pkt0 + (size_t)t * 512 + row * 8)       = lo2;
        *(uint2*)(pkt0 + (size_t)t * 512 + 256 + row * 8) = hi2;
    }
}

// ---------------------------------------------------------------------------
// Weight prep: W [K][N] fp32 -> 2*hi / 2*lo bf16 split in B-frag layout.
// ---------------------------------------------------------------------------
__global__ void split_transpose_all(const float* __restrict__ enc_W,
                                    const float* __restrict__ W_cells,
                                    bf16_t* __restrict__ W1h, bf16_t* __restrict__ W1l,
                                    bf16_t* __restrict__ W2h, bf16_t* __restrict__ W2l,
                                    bf16_t* __restrict__ W3h, bf16_t* __restrict__ W3l)
{
    const int N = 1024;
    const float* W;
    bf16_t *hi, *lo;
    int K;
    if (blockIdx.z == 0) {
        if (blockIdx.x >= 4) return;
        W = enc_W; hi = W1h; lo = W1l; K = 128;
    } else if (blockIdx.z == 1) {
        W = W_cells; hi = W2h; lo = W2l; K = 1024;
    } else {
        W = W_cells + (size_t)1024 * 1024; hi = W3h; lo = W3l; K = 1024;
    }
    const int NKB = K >> 4;
    __shared__ float tile[32][33];
    int k0 = blockIdx.x * 32, n0 = blockIdx.y * 32;
    int tx = threadIdx.x & 31, ty = threadIdx.x >> 5;
    for (int kk = ty; kk < 32; kk += 8)
        tile[kk][tx] = W[(size_t)(k0 + kk) * N + n0 + tx];
    __syncthreads();

    const int nn = tx;
    const int oc = ty;            // 0..7
    const int o2 = oc & 3;        // k-octet
    const bool isLo = (oc >> 2) != 0;
    const int kblk = (k0 >> 4) + (o2 >> 1);
    const int lane_in_packet = nn + 32 * (o2 & 1);

    frag_u f;
#pragma unroll
    for (int j = 0; j < 8; ++j) {
        float wv = tile[o2 * 8 + j][nn];
        bf16_t h = (bf16_t)wv;                          // original hi rounding
        bf16_t l = (bf16_t)(wv - (float)h);             // original lo rounding
        f.v[j] = isLo ? (bf16_t)(2.0f * (float)l)       // exact doubling
                      : (bf16_t)(2.0f * (float)h);
    }
    bf16_t* dst = (isLo ? lo : hi)
        + ((size_t)((n0 + nn) >> 5) * NKB + kblk) * 512 + lane_in_packet * 8;
    *(bf16x8*)dst = f.v;
}

// ---------------------------------------------------------------------------
// Fused MFMA GEMM + multistep LIF. R34 (= R28): full-LDS staging (ring-4),
// A packet [t][half][row][8B] (conflict-free ds_read_b64), counted waits,
// fused mean (LAST).
// ---------------------------------------------------------------------------
template <int K, bool LAST>
__global__ __launch_bounds__(256, 4)
void gemm_lif_mfma(const uint8_t* __restrict__ Abytes,
                   const bf16_t* __restrict__ Bh,
                   const bf16_t* __restrict__ Bl,
                   const float* __restrict__ bias,
                   uint8_t* __restrict__ Sbytes,
                   float* __restrict__ Out,
                   int M, int N)
{
    constexpr int NKB = K >> 4;                 // 8 or 64 (>= 4, even)
    // Ring slab (8KB/kb): [A m_local0 2KB | A m_local1 2KB |
    //                      B n0 hi 1KB | B n0 lo 1KB | B n1 hi | B n1 lo]
    __shared__ __align__(16) uint8_t ldsR[4][8192];      // 32KB ring
    __shared__ __align__(8) unsigned short sh[4][256];   // epilogue, per-wave

    const int tid = threadIdx.x;
    const int lane = tid & 63;
    const int wid = tid >> 6;
    const int l31 = lane & 31;
    const int half = lane >> 5;

    // XCD-locality swizzle (R18): XCD x owns m_t in [x*16, x*16+16);
    // walk nh(2) x mloc(16) x n8(8). Bijective.
    const int bid = blockIdx.x;
    const int xcd = bid & 7;
    const int j   = bid >> 3;                   // 0..255
    const int nh   = j >> 7;                    // 0..1
    const int r    = j & 127;
    const int mloc = r >> 3;                    // 0..15
    const int n_t  = nh * 8 + (r & 7);          // 0..15
    const int m_t  = xcd * 16 + mloc;           // 0..127

    const int m0 = m_t * 64, n0 = n_t * 64;
    const int wave_m = (wid & 1) * 32;
    const int wave_n = (wid >> 1) * 32;
    const int m_blk = (m0 + wave_m) >> 5;

    // ---- staging assignment: wave wid stages 2 of the 8 1KB chunks ----
    const uint8_t* src0;
    const uint8_t* src1;
    int sstride, d0off, d1off;
    if (wid < 2) {
        // A chunks: m_local = wid; 2KB/kb contiguous ([t][half][row][8B])
        const uint8_t* base = Abytes + ((size_t)(m0 >> 5) + wid) * NKB * 2048;
        src0 = base + (lane << 4);
        src1 = base + 1024 + (lane << 4);
        sstride = 2048;
        d0off = wid * 2048;
        d1off = d0off + 1024;
    } else {
        // B chunks: n_local = wid-2; hi and lo planes, 1KB/kb each
        const int nl = wid - 2;
        src0 = (const uint8_t*)(Bh + ((size_t)(n0 >> 5) + nl) * NKB * 512)
               + (lane << 4);
        src1 = (const uint8_t*)(Bl + ((size_t)(n0 >> 5) + nl) * NKB * 512)
               + (lane << 4);
        sstride = 1024;
        d0off = 4096 + nl * 2048;
        d1off = d0off + 1024;
    }
    uint8_t* ringBase = &ldsR[0][0];

    // ---- consumer fragment addresses ----
    // A: slot + (wid&1)*2048 + t*512 + half*256 + l31*8  (uint2 per t)
    //    -> 32-lane group covers banks 0..31 exactly 2x: conflict-free.
    // B: slot + 4096 + (wid>>1)*2048 (+1024 lo) + lane*16 (bf16x8)
    const int aRdOff = (wid & 1) * 2048 + half * 256 + l31 * 8;
    const int bRdOff = 4096 + ((wid >> 1) << 11) + (lane << 4);

    f32x16 acc[TSTEPS];
#pragma unroll
    for (int t = 0; t < TSTEPS; ++t)
        for (int rr = 0; rr < 16; ++rr) acc[t][rr] = 0.0f;

    uint2 fm[4];
    bf16x8 cfh, cfl;

#define STAGE2(kb_) {                                                         \
    __builtin_amdgcn_global_load_lds(                                         \
        (const __attribute__((address_space(1))) uint32_t*)                   \
            (src0 + (size_t)(kb_) * sstride),                                 \
        (__attribute__((address_space(3))) uint32_t*)                         \
            (ringBase + (((kb_) & 3) << 13) + d0off),                         \
        16, 0, 0);                                                            \
    __builtin_amdgcn_global_load_lds(                                         \
        (const __attribute__((address_space(1))) uint32_t*)                   \
            (src1 + (size_t)(kb_) * sstride),                                 \
        (__attribute__((address_space(3))) uint32_t*)                         \
            (ringBase + (((kb_) & 3) << 13) + d1off),                         \
        16, 0, 0);                                                            \
    }

#define FRAGRD(kb_) {                                                        \
        const uint8_t* sb = ringBase + (((kb_) & 3) << 13);                  \
        fm[0] = *(const uint2*)(sb + aRdOff);                                \
        fm[1] = *(const uint2*)(sb + aRdOff + 512);                          \
        fm[2] = *(const uint2*)(sb + aRdOff + 1024);                         \
        fm[3] = *(const uint2*)(sb + aRdOff + 1536);                         \
        cfh = *(const bf16x8*)(sb + bRdOff);                                 \
        cfl = *(const bf16x8*)(sb + bRdOff + 1024);                          \
    }

// byte 0x3F -> high byte of each 16-bit half = 0x3F00 = bf16 0.5 (1 perm/dw)
#define EXPANDF(a_, f_) {                                                    \
        (f_).d[0] = __builtin_amdgcn_perm((a_).x, 0u, 0x05000400u);          \
        (f_).d[1] = __builtin_amdgcn_perm((a_).x, 0u, 0x07000600u);          \
        (f_).d[2] = __builtin_amdgcn_perm((a_).y, 0u, 0x05000400u);          \
        (f_).d[3] = __builtin_amdgcn_perm((a_).y, 0u, 0x07000600u);          \
    }

#define MFMAS() {                                                            \
        frag_u af0, af1, af2, af3;                                           \
        EXPANDF(fm[0], af0);                                                 \
        EXPANDF(fm[1], af1);                                                 \
        EXPANDF(fm[2], af2);                                                 \
        EXPANDF(fm[3], af3);                                                 \
        acc[0] = __builtin_amdgcn_mfma_f32_32x32x16_bf16(af0.v, cfh, acc[0], 0, 0, 0); \
        acc[1] = __builtin_amdgcn_mfma_f32_32x32x16_bf16(af1.v, cfh, acc[1], 0, 0, 0); \
        acc[2] = __builtin_amdgcn_mfma_f32_32x32x16_bf16(af2.v, cfh, acc[2], 0, 0, 0); \
        acc[3] = __builtin_amdgcn_mfma_f32_32x32x16_bf16(af3.v, cfh, acc[3], 0, 0, 0); \
        acc[0] = __builtin_amdgcn_mfma_f32_32x32x16_bf16(af0.v, cfl, acc[0], 0, 0, 0); \
        acc[1] = __builtin_amdgcn_mfma_f32_32x32x16_bf16(af1.v, cfl, acc[1], 0, 0, 0); \
        acc[2] = __builtin_amdgcn_mfma_f32_32x32x16_bf16(af2.v, cfl, acc[2], 0, 0, 0); \
        acc[3] = __builtin_amdgcn_mfma_f32_32x32x16_bf16(af3.v, cfl, acc[3], 0, 0, 0); \
    }

    // Prologue: stage kb 0,1 (slots 0,1); drain stage(0); read frags(0).
    STAGE2(0);
    STAGE2(1);
    __builtin_amdgcn_s_waitcnt(WT_VM2);      // drains stage(0)
    asm volatile("" ::: "memory");
    __builtin_amdgcn_s_barrier();
    asm volatile("" ::: "memory");
    FRAGRD(0);

    // Steady state: step kb computes kb, stages kb+2, publishes kb+1.
    // vmcnt(2): outstanding = stage(kb+1) 2 + stage(kb+2) 2 -> drains
    // stage(kb+1) (one full step of latency cover). lgkm(0): drains the
    // hoisted frag reads for kb. Barrier publishes slot (kb+1)&3.
    // Ring reuse: slot (kb+2)&3 held kb-2, whose ds_reads were lgkm-drained
    // two barriers before this STAGE2 issues.
    for (int kb = 0; kb < NKB - 2; ++kb) {
        STAGE2(kb + 2);
        __builtin_amdgcn_s_waitcnt(WT_VM2_LG0);
        asm volatile("" ::: "memory");
        MFMAS();
        __builtin_amdgcn_s_barrier();
        asm volatile("" ::: "memory");
        FRAGRD(kb + 1);
    }
    // Step NKB-2: nothing to stage; drain stage(NKB-1) + frag reads.
    __builtin_amdgcn_s_waitcnt(WT_VM0_LG0);
    asm volatile("" ::: "memory");
    MFMAS();
    __builtin_amdgcn_s_barrier();
    asm volatile("" ::: "memory");
    FRAGRD(NKB - 1);
    // Step NKB-1: final.
    __builtin_amdgcn_s_waitcnt(WT_LG0);
    asm volatile("" ::: "memory");
    MFMAS();

#undef MFMAS
#undef EXPANDF
#undef FRAGRD
#undef STAGE2

    // --- LIF epilogue: t-scan in registers (XLA-exact arithmetic) ---
    const float bv = bias[n0 + wave_n + l31];
    f32x16 vmem;
#pragma unroll
    for (int rr = 0; rr < 16; ++rr) vmem[rr] = 0.0f;
    uint64_t bits = 0ull;
    unsigned short* myt = &sh[wid][0];          // [row][kb][t] = [32][2][4]

    const int NKBo = N >> 4;
    const int kbase = (n0 + wave_n) >> 4;

    for (int t = 0; t < TSTEPS; ++t) {
#pragma unroll
        for (int rr = 0; rr < 16; ++rr) {
            float y = __fadd_rn(acc[t][rr], bv);
            float vv = vmem[rr];
            vv = __fadd_rn(vv, __fmul_rn(__fsub_rn(y, vv), 0.5f));
            bool sp = (vv >= 1.0f);
            vmem[rr] = sp ? 0.0f : vv;
            if (LAST) {
                bits |= sp ? (1ull << (rr * 4 + t)) : 0ull;
            } else {
                unsigned long long b = __ballot(sp);
                if (l31 == 0) {
                    uint32_t hb = (uint32_t)(b >> (half * 32));
                    int rowi = (rr & 3) + 8 * (rr >> 2) + 4 * half;
                    myt[(rowi * 2 + 0) * 4 + t] = (unsigned short)hb;
                    myt[(rowi * 2 + 1) * 4 + t] = (unsigned short)(hb >> 16);
                }
            }
        }
    }

    if (LAST) {
        // Out writes + fused mean-over-L. All values multiples of 2^-11,
        // totals <= 1 -> fp32 atomics exact and order-independent.
        float psum = 0.0f;
#pragma unroll
        for (int rr = 0; rr < 16; ++rr) {
            int m_r = (rr & 3) + 8 * (rr >> 2) + 4 * half;
            int m = m0 + wave_m + m_r;
            int n = n0 + wave_n + l31;
            int cnt = __popc((unsigned)((bits >> (rr * 4)) & 0xFull));
            float val = 0.25f * (float)cnt;
            Out[(size_t)m * N + n] = val;
            psum += val;                       // exact: multiples of 0.25
        }
        // combine the two halves (same n, other 16 m's of the 32-row blk)
        psum += __shfl_xor(psum, 32, 64);
        if (half == 0) {
            float* out2 = Out + (size_t)M * N;
            int b = m0 >> 9;                   // m0 multiple of 64; L = 512
            int n = n0 + wave_n + l31;
            atomicAdd(out2 + (size_t)b * N + n, psum * (1.0f / 512.0f));
        }
    } else {
        // Emit next-stage A in [t][half][row][8B] packet layout: thread
        // (l31 = row) writes k0-7 at row*8 and k8-15 at 256+row*8 within
        // packet [m_blk][kbase+half][t].
        const ushort4v pk = *(const ushort4v*)&myt[(l31 * 2 + half) * 4];
        uint8_t* pkt0 = Sbytes
            + ((size_t)m_blk * NKBo + kbase + half) * 4 * 512;
#pragma unroll
        for (int t = 0; t < TSTEPS; ++t) {
            uint32_t m16 = pk[t];
            uint32_t b0 = (((m16      ) & 0xFu) * 0x00204081u & 0x01010101u) * 0x3Fu;
            uint32_t b1 = (((m16 >>  4) & 0xFu) * 0x00204081u & 0x01010101u) * 0x3Fu;
            uint32_t b2 = (((m16 >>  8) & 0xFu) * 0x00204081u & 0x01010101u) * 0x3Fu;
            uint32_t b3 = (((m16 >> 12) & 0xFu) * 0x00204081u & 0x01010101u) * 0x3Fu;
            uint2 lo2; lo2.x = b0; lo2.y = b1;
            uint2 hi2; hi2.x = b2; hi2.y = b3;
            *(uint2*)(pkt0 + (size_t)t * 512 + l31 * 8)       = lo2;
            *(uint2*)(pkt0 + (size_t)t * 512 + 256 + l31 * 8) = hi2;
        }
    }
}

// ---------------------------------------------------------------------------
// Zero out2 (graph-capture-safe replacement for hipMemsetAsync).
// ---------------------------------------------------------------------------
__global__ void zero_out2(float* __restrict__ out2, int n)
{
    int i = blockIdx.x * blockDim.x + threadIdx.x;
    if (i < n) out2[i] = 0.0f;
}

// ---------------------------------------------------------------------------
extern "C" void kernel_launch(void* const* d_in, const int* in_sizes, int n_in,
                              void* d_out, int out_size, void* d_ws, size_t ws_size,
                              hipStream_t stream)
{
    const float* inputs  = (const float*)d_in[0];  // [16,512,128]
    const float* enc_W   = (const float*)d_in[1];  // [128,1024]
    const float* enc_b   = (const float*)d_in[2];  // [1024]
    const float* W_cells = (const float*)d_in[3];  // [2,1024,1024]
    const float* b_cells = (const float*)d_in[4];  // [2,1024]

    const int B = 16, L = 512, C = 128, D = 1024;
    const int M = B * L;  // 8192

    // ws: s1 i8 4MB | W1h/l 0.5MB | W2h/l 4MB | W3h/l 4MB | h0 32MB | h1 32MB
    char* ws = (char*)d_ws;
    size_t off = 0;
    uint8_t* s1 = (uint8_t*)(ws + off);
    off += (size_t)(M / 32) * (C / 16) * 4 * 32 * 16;
    bf16_t* W1h = (bf16_t*)(ws + off); off += (size_t)C * D * 2;
    bf16_t* W1l = (bf16_t*)(ws + off); off += (size_t)C * D * 2;
    bf16_t* W2h = (bf16_t*)(ws + off); off += (size_t)D * D * 2;
    bf16_t* W2l = (bf16_t*)(ws + off); off += (size_t)D * D * 2;
    bf16_t* W3h = (bf16_t*)(ws + off); off += (size_t)D * D * 2;
    bf16_t* W3l = (bf16_t*)(ws + off); off += (size_t)D * D * 2;
    uint8_t* h0 = (uint8_t*)(ws + off);
    off += (size_t)(M / 32) * (D / 16) * 4 * 32 * 16;
    uint8_t* h1 = (uint8_t*)(ws + off);

    float* out  = (float*)d_out;          // [M, D]
    float* out2 = out + (size_t)M * D;    // [B, D]

    split_transpose_all<<<dim3(32, 32, 3), 256, 0, stream>>>(
        enc_W, W_cells, W1h, W1l, W2h, W2l, W3h, W3l);

    spike_encode_i8<<<256, 256, 0, stream>>>(inputs, s1);

    zero_out2<<<(B * D + 255) / 256, 256, 0, stream>>>(out2, B * D);

    const int nblocks = (M / 64) * (D / 64);   // 2048
    gemm_lif_mfma<128, false><<<nblocks, 256, 0, stream>>>(
        s1, W1h, W1l, enc_b, h0, nullptr, M, D);
    gemm_lif_mfma<1024, false><<<nblocks, 256, 0, stream>>>(
        h0, W2h, W2l, b_cells, h1, nullptr, M, D);
    gemm_lif_mfma<1024, true><<<nblocks, 256, 0, stream>>>(
        h1, W3h, W3l, b_cells + D, nullptr, out, M, D);
}